// Round 3
// baseline (186.833 us; speedup 1.0000x reference)
//
#include <hip/hip_runtime.h>
#include <hip/hip_bf16.h>
#include <math.h>

#define B_  4
#define T_  4096
#define C_  1024
#define HS_ 128

using bf16x8 = __attribute__((ext_vector_type(8))) __bf16;
using bf16x4 = __attribute__((ext_vector_type(4))) __bf16;
using f32x4  = __attribute__((ext_vector_type(4))) float;

#define MFMA(a, b, c) __builtin_amdgcn_mfma_f32_16x16x32_bf16(a, b, c, 0, 0, 0)

// fast exp2 via v_exp_f32; trailing s_nop covers the 1-wait-state trans hazard
__device__ inline float fexp2(float x) {
  float r;
  asm volatile("v_exp_f32 %0, %1\n\ts_nop 0" : "=v"(r) : "v"(x));
  return r;
}

// ---------------------------------------------------------------------------
// Kernel 1: W fp32 [1024][128] -> Wt bf16 [3][128][1024] via LDS transpose.
// m=0: Wq scaled by 1/sqrt(128) * log2(e)  (exp2-domain softmax).
// ---------------------------------------------------------------------------
__global__ __launch_bounds__(256) void prep_w_kernel(
    const float* __restrict__ Wk, const float* __restrict__ Wq,
    const float* __restrict__ Wv, __bf16* __restrict__ Wt) {
  const int m  = blockIdx.x >> 4;        // 0..2
  const int k0 = (blockIdx.x & 15) * 64; // k-slab base
  const float* W = (m == 0) ? Wq : ((m == 1) ? Wk : Wv);
  const float scale = (m == 0) ? (0.08838834764831845f * 1.4426950408889634f) : 1.0f;
  __shared__ __bf16 tile[128][72];       // [n][k-within-slab], padded
  const int t = threadIdx.x;
#pragma unroll
  for (int p = 0; p < 8; ++p) {
    int e  = p * 1024 + t * 4;
    int r  = e >> 7;                     // 0..63
    int cc = e & 127;
    float4 w = *reinterpret_cast<const float4*>(&W[(size_t)(k0 + r) * HS_ + cc]);
    tile[cc + 0][r] = (__bf16)(w.x * scale);
    tile[cc + 1][r] = (__bf16)(w.y * scale);
    tile[cc + 2][r] = (__bf16)(w.z * scale);
    tile[cc + 3][r] = (__bf16)(w.w * scale);
  }
  __syncthreads();
#pragma unroll
  for (int p = 0; p < 4; ++p) {
    int e  = p * 2048 + t * 8;
    int n  = e >> 6;                     // 0..127
    int kk = e & 63;
    bf16x8 v;
#pragma unroll
    for (int jj = 0; jj < 8; ++jj) v[jj] = tile[n][kk + jj];
    *reinterpret_cast<bf16x8*>(&Wt[((size_t)m * 128 + n) * C_ + k0 + kk]) = v;
  }
}

__device__ inline bf16x8 cvt8p(float4 u, float4 v) {
  bf16x8 r;
  r[0] = (__bf16)u.x; r[1] = (__bf16)u.y; r[2] = (__bf16)u.z; r[3] = (__bf16)u.w;
  r[4] = (__bf16)v.x; r[5] = (__bf16)v.y; r[6] = (__bf16)v.z; r[7] = (__bf16)v.w;
  return r;
}

// ---------------------------------------------------------------------------
// Kernel 2: projections. 1024 blocks x 16 rows, 4 waves, 6 (m,nt) units each.
// 2-stage software pipeline of x (fp32->bf16 in-reg) and W fragments.
// Q,K row-major bf16 [B*T][128]; V transposed [B][128][T].
// ---------------------------------------------------------------------------
__global__ __launch_bounds__(256, 4) void proj_kernel(
    const float* __restrict__ x, const __bf16* __restrict__ Wt,
    __bf16* __restrict__ Qb, __bf16* __restrict__ Kb, __bf16* __restrict__ Vt) {
  const int tid = threadIdx.x;
  const int wid = tid >> 6;
  const int l   = tid & 63;
  const int c   = l & 15;
  const int g   = l >> 4;
  const int rbase = blockIdx.x * 16;

  f32x4 acc[6];
#pragma unroll
  for (int i = 0; i < 6; ++i) acc[i] = 0.f;

  const float* xr = x + (size_t)(rbase + c) * C_ + g * 8;
  const __bf16* wb[6];
#pragma unroll
  for (int i = 0; i < 6; ++i) {
    int u = wid * 6 + i;
    wb[i] = Wt + ((size_t)(u >> 3) * 128 + (u & 7) * 16 + c) * C_ + g * 8;
  }

  float4 u0 = *reinterpret_cast<const float4*>(xr);
  float4 v0 = *reinterpret_cast<const float4*>(xr + 4);
  bf16x8 b0[6];
#pragma unroll
  for (int i = 0; i < 6; ++i) b0[i] = *reinterpret_cast<const bf16x8*>(wb[i]);

  for (int cb = 0; cb < C_; cb += 64) {
    float4 u1, v1; bf16x8 b1[6];
    {
      const float* xp = xr + cb + 32;
      u1 = *reinterpret_cast<const float4*>(xp);
      v1 = *reinterpret_cast<const float4*>(xp + 4);
#pragma unroll
      for (int i = 0; i < 6; ++i) b1[i] = *reinterpret_cast<const bf16x8*>(wb[i] + cb + 32);
    }
    bf16x8 a = cvt8p(u0, v0);
#pragma unroll
    for (int i = 0; i < 6; ++i) acc[i] = MFMA(a, b0[i], acc[i]);
    if (cb + 64 < C_) {
      const float* xp = xr + cb + 64;
      u0 = *reinterpret_cast<const float4*>(xp);
      v0 = *reinterpret_cast<const float4*>(xp + 4);
#pragma unroll
      for (int i = 0; i < 6; ++i) b0[i] = *reinterpret_cast<const bf16x8*>(wb[i] + cb + 64);
    }
    a = cvt8p(u1, v1);
#pragma unroll
    for (int i = 0; i < 6; ++i) acc[i] = MFMA(a, b1[i], acc[i]);
  }

#pragma unroll
  for (int i = 0; i < 6; ++i) {
    const int u = wid * 6 + i;
    const int m = u >> 3, nt = u & 7;
    if (m < 2) {
      __bf16* dst = (m == 0) ? Qb : Kb;
#pragma unroll
      for (int rr = 0; rr < 4; ++rr)
        dst[(size_t)(rbase + 4 * g + rr) * HS_ + nt * 16 + c] = (__bf16)acc[i][rr];
    } else {
      int row = rbase + 4 * g;
      int bb  = row >> 12;
      int t   = row & 4095;
      bf16x4 v4;
#pragma unroll
      for (int rr = 0; rr < 4; ++rr) v4[rr] = (__bf16)acc[i][rr];
      *reinterpret_cast<bf16x4*>(Vt + ((size_t)bb * HS_ + nt * 16 + c) * T_ + t) = v4;
    }
  }
}

// ---------------------------------------------------------------------------
// Kernel 3: causal flash attention. 4 waves/block; each wave owns the FULL
// 32 q-rows (acc[2][8]) and a 4-way kt split (kt = wid, wid+4, ...).
// S^T = mfma(K_perm, Q^T): softmax stats lane-column-local; P per-lane IS
// the PV B-fragment. K next-tile register prefetch; V loads fly under
// softmax VALU. exp2-domain (log2e folded into Wq). 4-wave LDS combine.
// b = (bid&7)>>1 gives batch->XCD affinity (K/V working set < 4MB L2/XCD).
// ---------------------------------------------------------------------------
__global__ __launch_bounds__(256, 2) void attn_kernel(
    const __bf16* __restrict__ Qb, const __bf16* __restrict__ Kb,
    const __bf16* __restrict__ Vt, float* __restrict__ out) {
  __shared__ float sm[4][32];
  __shared__ float sl[4][32];
  __shared__ float bufA[32][132];
  __shared__ float bufB[32][132];

  const int tid = threadIdx.x;
  const int wid = tid >> 6;
  const int l   = tid & 63;
  const int c   = l & 15;
  const int g   = l >> 4;
  const int bid = blockIdx.x;
  const int b   = (bid & 7) >> 1;                    // XCD-affine batch
  const int j   = ((bid >> 3) << 1) | (bid & 1);     // 0..127
  const int qt  = (j < 64) ? (127 - j) : (j - 64);   // big tiles dispatched first
  const int qb  = qt * 32;
  const int kp  = ((l & 12) << 1) | (l & 3);         // A-slot m -> key 8*(m>>2)+(m&3)

  const __bf16* Qp = Qb + (size_t)b * T_ * HS_;
  const __bf16* Kp = Kb + (size_t)b * T_ * HS_;
  const __bf16* Vp = Vt + (size_t)b * HS_ * T_;

  bf16x8 qf[2][4];
#pragma unroll
  for (int rt = 0; rt < 2; ++rt)
#pragma unroll
    for (int cs = 0; cs < 4; ++cs)
      qf[rt][cs] = *reinterpret_cast<const bf16x8*>(
          Qp + (size_t)(qb + rt * 16 + c) * HS_ + cs * 32 + g * 8);

  f32x4 acc[2][8];
#pragma unroll
  for (int i = 0; i < 2; ++i)
#pragma unroll
    for (int d = 0; d < 8; ++d) acc[i][d] = 0.f;
  float mrun[2] = {-INFINITY, -INFINITY};
  float lrun[2] = {0.f, 0.f};

  if (wid <= qt) {
    bf16x8 kreg[8];
    auto kload = [&](int kt) {
      const __bf16* kr = Kp + (size_t)(kt * 32 + kp) * HS_;
#pragma unroll
      for (int cs = 0; cs < 4; ++cs) {
        kreg[2 * cs]     = *reinterpret_cast<const bf16x8*>(kr + cs * 32 + g * 8);
        kreg[2 * cs + 1] = *reinterpret_cast<const bf16x8*>(kr + 4 * HS_ + cs * 32 + g * 8);
      }
    };
    kload(wid);

    for (int kt = wid; kt <= qt; kt += 4) {
      f32x4 s00 = 0.f, s01 = 0.f, s10 = 0.f, s11 = 0.f;
      __builtin_amdgcn_s_setprio(1);
#pragma unroll
      for (int cs = 0; cs < 4; ++cs) {
        s00 = MFMA(kreg[2 * cs], qf[0][cs], s00);
        s01 = MFMA(kreg[2 * cs + 1], qf[0][cs], s01);
        s10 = MFMA(kreg[2 * cs], qf[1][cs], s10);
        s11 = MFMA(kreg[2 * cs + 1], qf[1][cs], s11);
      }
      __builtin_amdgcn_s_setprio(0);

      if (kt + 4 <= qt) kload(kt + 4);        // prefetch next K tile

      bf16x8 vf[8];
      const __bf16* vr = Vp + kt * 32 + g * 8;
#pragma unroll
      for (int db = 0; db < 8; ++db)
        vf[db] = *reinterpret_cast<const bf16x8*>(vr + (size_t)(db * 16 + c) * T_);

      const bool maskt = (kt == qt);           // only the diagonal tile
      bf16x8 pb[2];
#pragma unroll
      for (int rt = 0; rt < 2; ++rt) {
        float p[8];
        const f32x4 sa = rt ? s10 : s00;
        const f32x4 sb = rt ? s11 : s01;
#pragma unroll
        for (int rr = 0; rr < 4; ++rr) { p[rr] = sa[rr]; p[4 + rr] = sb[rr]; }
        if (maskt) {
          const int lim = rt * 16 + c;
#pragma unroll
          for (int jj = 0; jj < 8; ++jj)
            if (8 * g + jj > lim) p[jj] = -INFINITY;
        }
        float t0 = fmaxf(fmaxf(p[0], p[1]), p[2]);
        float t1 = fmaxf(fmaxf(p[3], p[4]), p[5]);
        float t2 = fmaxf(fmaxf(p[6], p[7]), t0);
        float tmax = fmaxf(t1, t2);
        tmax = fmaxf(tmax, __shfl_xor(tmax, 16));
        tmax = fmaxf(tmax, __shfl_xor(tmax, 32));

        if (!__all(tmax <= mrun[rt] + 11.5415603f)) {   // defer-max, log2 units
          float mnew = fmaxf(mrun[rt], tmax);
          float al   = fexp2(mrun[rt] - mnew);
          mrun[rt] = mnew;
          lrun[rt] *= al;
#pragma unroll
          for (int db = 0; db < 8; ++db) acc[rt][db] *= al;
        }
        const float mc = mrun[rt];
#pragma unroll
        for (int jj = 0; jj < 8; ++jj) p[jj] = fexp2(p[jj] - mc);
        float ts = ((p[0] + p[1]) + (p[2] + p[3])) + ((p[4] + p[5]) + (p[6] + p[7]));
        ts += __shfl_xor(ts, 16);
        ts += __shfl_xor(ts, 32);
        lrun[rt] += ts;
#pragma unroll
        for (int jj = 0; jj < 8; ++jj) pb[rt][jj] = (__bf16)p[jj];
      }

      __builtin_amdgcn_s_setprio(1);
#pragma unroll
      for (int db = 0; db < 8; ++db) {
        acc[0][db] = MFMA(vf[db], pb[0], acc[0][db]);
        acc[1][db] = MFMA(vf[db], pb[1], acc[1][db]);
      }
      __builtin_amdgcn_s_setprio(0);
    }
  }

  // ---- combine the 4 waves' partial (m, l, O) ----
  if (g == 0) {
    sm[wid][c] = mrun[0]; sm[wid][16 + c] = mrun[1];
    sl[wid][c] = lrun[0]; sl[wid][16 + c] = lrun[1];
  }
  __syncthreads();

  float linv[2];
#pragma unroll
  for (int rt = 0; rt < 2; ++rt) {
    const int q = rt * 16 + c;
    float ms = fmaxf(fmaxf(sm[0][q], sm[1][q]), fmaxf(sm[2][q], sm[3][q]));
    float ls = fexp2(sm[0][q] - ms) * sl[0][q] + fexp2(sm[1][q] - ms) * sl[1][q]
             + fexp2(sm[2][q] - ms) * sl[2][q] + fexp2(sm[3][q] - ms) * sl[3][q];
    float al = fexp2(mrun[rt] - ms);
#pragma unroll
    for (int db = 0; db < 8; ++db) acc[rt][db] *= al;
    linv[rt] = 1.0f / ls;
  }

  auto store_buf = [&](float(*buf)[132]) {
#pragma unroll
    for (int rt = 0; rt < 2; ++rt)
#pragma unroll
      for (int db = 0; db < 8; ++db)
        *reinterpret_cast<f32x4*>(&buf[rt * 16 + c][db * 16 + 4 * g]) = acc[rt][db];
  };
  auto add_buf = [&](float(*buf)[132]) {
#pragma unroll
    for (int rt = 0; rt < 2; ++rt)
#pragma unroll
      for (int db = 0; db < 8; ++db)
        acc[rt][db] += *reinterpret_cast<const f32x4*>(&buf[rt * 16 + c][db * 16 + 4 * g]);
  };

  if (wid == 2) store_buf(bufA);
  if (wid == 3) store_buf(bufB);
  __syncthreads();
  if (wid == 0) add_buf(bufA);
  if (wid == 1) add_buf(bufB);
  __syncthreads();
  if (wid == 1) store_buf(bufA);
  __syncthreads();
  if (wid == 0) {
    add_buf(bufA);
    float* op = out + ((size_t)b * T_ + qb) * HS_;
#pragma unroll
    for (int rt = 0; rt < 2; ++rt)
#pragma unroll
      for (int db = 0; db < 8; ++db) {
        f32x4 v = acc[rt][db] * linv[rt];
        *reinterpret_cast<f32x4*>(op + (size_t)(rt * 16 + c) * HS_ + db * 16 + 4 * g) = v;
      }
  }
}

// ---------------------------------------------------------------------------
extern "C" void kernel_launch(void* const* d_in, const int* in_sizes, int n_in,
                              void* d_out, int out_size, void* d_ws, size_t ws_size,
                              hipStream_t stream) {
  const float* x  = (const float*)d_in[0];
  const float* Wk = (const float*)d_in[1];
  const float* Wq = (const float*)d_in[2];
  const float* Wv = (const float*)d_in[3];
  float* out = (float*)d_out;

  char* ws = (char*)d_ws;
  __bf16* Wt = (__bf16*)ws;                              // 768 KiB
  __bf16* Qb = (__bf16*)(ws + 786432);                   // 4 MiB
  __bf16* Kb = (__bf16*)(ws + 786432 + 4194304);         // 4 MiB
  __bf16* Vt = (__bf16*)(ws + 786432 + 8388608);         // 4 MiB (transposed V)

  prep_w_kernel<<<48, 256, 0, stream>>>(Wk, Wq, Wv, Wt);
  proj_kernel<<<1024, 256, 0, stream>>>(x, Wt, Qb, Kb, Vt);
  attn_kernel<<<512, 256, 0, stream>>>(Qb, Kb, Vt, out);
}

// Round 4
// 173.408 us; speedup vs baseline: 1.0774x; 1.0774x over previous
//
#include <hip/hip_runtime.h>
#include <hip/hip_bf16.h>
#include <math.h>

#define B_  4
#define T_  4096
#define C_  1024
#define HS_ 128

using bf16x8 = __attribute__((ext_vector_type(8))) __bf16;
using bf16x4 = __attribute__((ext_vector_type(4))) __bf16;
using f32x4  = __attribute__((ext_vector_type(4))) float;

#define MFMA(a, b, c) __builtin_amdgcn_mfma_f32_16x16x32_bf16(a, b, c, 0, 0, 0)

// fast exp2 via v_exp_f32; trailing s_nop covers the 1-wait-state trans hazard
__device__ inline float fexp2(float x) {
  float r;
  asm volatile("v_exp_f32 %0, %1\n\ts_nop 0" : "=v"(r) : "v"(x));
  return r;
}

// ---------------------------------------------------------------------------
// Kernel 1: W fp32 [1024][128] -> Wt bf16 [3][128][1024] via LDS transpose.
// m=0: Wq scaled by 1/sqrt(128) * log2(e)  (exp2-domain softmax).
// ---------------------------------------------------------------------------
__global__ __launch_bounds__(256) void prep_w_kernel(
    const float* __restrict__ Wk, const float* __restrict__ Wq,
    const float* __restrict__ Wv, __bf16* __restrict__ Wt) {
  const int m  = blockIdx.x >> 4;        // 0..2
  const int k0 = (blockIdx.x & 15) * 64; // k-slab base
  const float* W = (m == 0) ? Wq : ((m == 1) ? Wk : Wv);
  const float scale = (m == 0) ? (0.08838834764831845f * 1.4426950408889634f) : 1.0f;
  __shared__ __bf16 tile[128][72];       // [n][k-within-slab], padded
  const int t = threadIdx.x;
#pragma unroll
  for (int p = 0; p < 8; ++p) {
    int e  = p * 1024 + t * 4;
    int r  = e >> 7;                     // 0..63
    int cc = e & 127;
    float4 w = *reinterpret_cast<const float4*>(&W[(size_t)(k0 + r) * HS_ + cc]);
    tile[cc + 0][r] = (__bf16)(w.x * scale);
    tile[cc + 1][r] = (__bf16)(w.y * scale);
    tile[cc + 2][r] = (__bf16)(w.z * scale);
    tile[cc + 3][r] = (__bf16)(w.w * scale);
  }
  __syncthreads();
#pragma unroll
  for (int p = 0; p < 4; ++p) {
    int e  = p * 2048 + t * 8;
    int n  = e >> 6;                     // 0..127
    int kk = e & 63;
    bf16x8 v;
#pragma unroll
    for (int jj = 0; jj < 8; ++jj) v[jj] = tile[n][kk + jj];
    *reinterpret_cast<bf16x8*>(&Wt[((size_t)m * 128 + n) * C_ + k0 + kk]) = v;
  }
}

__device__ inline bf16x8 cvt8p(float4 u, float4 v) {
  bf16x8 r;
  r[0] = (__bf16)u.x; r[1] = (__bf16)u.y; r[2] = (__bf16)u.z; r[3] = (__bf16)u.w;
  r[4] = (__bf16)v.x; r[5] = (__bf16)v.y; r[6] = (__bf16)v.z; r[7] = (__bf16)v.w;
  return r;
}

// ---------------------------------------------------------------------------
// Kernel 2: projections. 512 blocks x 32 rows, 8 waves; wave owns 3 (m,nt)
// units (acc[3][2] -> only 24 accum regs; ~95 live arch VGPRs, NO launch-
// bounds cap: the (N,4) cap forced 64 arch VGPRs + spills in rounds 2-3).
// 2-stage software pipeline of x (fp32->bf16 in-reg) and W fragments.
// Q,K row-major bf16 [B*T][128]; V transposed [B][128][T].
// ---------------------------------------------------------------------------
__global__ __launch_bounds__(512) void proj_kernel(
    const float* __restrict__ x, const __bf16* __restrict__ Wt,
    __bf16* __restrict__ Qb, __bf16* __restrict__ Kb, __bf16* __restrict__ Vt) {
  const int tid = threadIdx.x;
  const int wid = tid >> 6;      // 0..7
  const int l   = tid & 63;
  const int c   = l & 15;        // A-row / B-col slot
  const int g   = l >> 4;        // k-group
  const int rbase = blockIdx.x * 32;

  f32x4 acc[3][2];
#pragma unroll
  for (int i = 0; i < 3; ++i) { acc[i][0] = 0.f; acc[i][1] = 0.f; }

  const float* xr0 = x + (size_t)(rbase + c) * C_ + g * 8;
  const float* xr1 = xr0 + 16 * C_;
  const __bf16* wb[3];
#pragma unroll
  for (int i = 0; i < 3; ++i) {
    int u = wid * 3 + i;
    wb[i] = Wt + ((size_t)(u >> 3) * 128 + (u & 7) * 16 + c) * C_ + g * 8;
  }

  float4 xu0 = *reinterpret_cast<const float4*>(xr0);
  float4 xv0 = *reinterpret_cast<const float4*>(xr0 + 4);
  float4 yu0 = *reinterpret_cast<const float4*>(xr1);
  float4 yv0 = *reinterpret_cast<const float4*>(xr1 + 4);
  bf16x8 b0[3];
#pragma unroll
  for (int i = 0; i < 3; ++i) b0[i] = *reinterpret_cast<const bf16x8*>(wb[i]);

  for (int cb = 0; cb < C_; cb += 64) {
    // prefetch stage B (cb+32) — always in-bounds (cb <= 960)
    float4 xu1, xv1, yu1, yv1; bf16x8 b1[3];
    {
      const float* p0 = xr0 + cb + 32;
      const float* p1 = xr1 + cb + 32;
      xu1 = *reinterpret_cast<const float4*>(p0);
      xv1 = *reinterpret_cast<const float4*>(p0 + 4);
      yu1 = *reinterpret_cast<const float4*>(p1);
      yv1 = *reinterpret_cast<const float4*>(p1 + 4);
#pragma unroll
      for (int i = 0; i < 3; ++i) b1[i] = *reinterpret_cast<const bf16x8*>(wb[i] + cb + 32);
    }
    // compute stage A
    {
      bf16x8 a0 = cvt8p(xu0, xv0);
      bf16x8 a1 = cvt8p(yu0, yv0);
#pragma unroll
      for (int i = 0; i < 3; ++i) {
        acc[i][0] = MFMA(a0, b0[i], acc[i][0]);
        acc[i][1] = MFMA(a1, b0[i], acc[i][1]);
      }
    }
    // prefetch stage A of next iter (cb+64)
    if (cb + 64 < C_) {
      const float* p0 = xr0 + cb + 64;
      const float* p1 = xr1 + cb + 64;
      xu0 = *reinterpret_cast<const float4*>(p0);
      xv0 = *reinterpret_cast<const float4*>(p0 + 4);
      yu0 = *reinterpret_cast<const float4*>(p1);
      yv0 = *reinterpret_cast<const float4*>(p1 + 4);
#pragma unroll
      for (int i = 0; i < 3; ++i) b0[i] = *reinterpret_cast<const bf16x8*>(wb[i] + cb + 64);
    }
    // compute stage B
    {
      bf16x8 a0 = cvt8p(xu1, xv1);
      bf16x8 a1 = cvt8p(yu1, yv1);
#pragma unroll
      for (int i = 0; i < 3; ++i) {
        acc[i][0] = MFMA(a0, b1[i], acc[i][0]);
        acc[i][1] = MFMA(a1, b1[i], acc[i][1]);
      }
    }
  }

#pragma unroll
  for (int i = 0; i < 3; ++i) {
    const int u = wid * 3 + i;
    const int m = u >> 3, nt = u & 7;
    if (m < 2) {
      __bf16* dst = (m == 0) ? Qb : Kb;
#pragma unroll
      for (int rt = 0; rt < 2; ++rt)
#pragma unroll
        for (int rr = 0; rr < 4; ++rr)
          dst[(size_t)(rbase + rt * 16 + 4 * g + rr) * HS_ + nt * 16 + c] =
              (__bf16)acc[i][rt][rr];
    } else {
#pragma unroll
      for (int rt = 0; rt < 2; ++rt) {
        int row = rbase + rt * 16 + 4 * g;
        int bb  = row >> 12;
        int t   = row & 4095;
        bf16x4 v4;
#pragma unroll
        for (int rr = 0; rr < 4; ++rr) v4[rr] = (__bf16)acc[i][rt][rr];
        *reinterpret_cast<bf16x4*>(Vt + ((size_t)bb * HS_ + nt * 16 + c) * T_ + t) = v4;
      }
    }
  }
}

// ---------------------------------------------------------------------------
// Kernel 3: causal flash attention. 4 waves/block; each wave owns the FULL
// 32 q-rows (acc[2][8]) and a 4-way kt split (kt = wid, wid+4, ...).
// S^T = mfma(K_perm, Q^T): softmax stats lane-column-local; P per-lane IS
// the PV B-fragment. K next-tile register prefetch; V loads fly under
// softmax VALU. exp2-domain (log2e folded into Wq). 4-wave LDS combine.
// b = (bid&7)>>1 gives batch->XCD affinity (K/V working set < 4MB L2/XCD).
// ---------------------------------------------------------------------------
__global__ __launch_bounds__(256, 2) void attn_kernel(
    const __bf16* __restrict__ Qb, const __bf16* __restrict__ Kb,
    const __bf16* __restrict__ Vt, float* __restrict__ out) {
  __shared__ float sm[4][32];
  __shared__ float sl[4][32];
  __shared__ float bufA[32][132];
  __shared__ float bufB[32][132];

  const int tid = threadIdx.x;
  const int wid = tid >> 6;
  const int l   = tid & 63;
  const int c   = l & 15;
  const int g   = l >> 4;
  const int bid = blockIdx.x;
  const int b   = (bid & 7) >> 1;                    // XCD-affine batch
  const int j   = ((bid >> 3) << 1) | (bid & 1);     // 0..127
  const int qt  = (j < 64) ? (127 - j) : (j - 64);   // big tiles dispatched first
  const int qb  = qt * 32;
  const int kp  = ((l & 12) << 1) | (l & 3);         // A-slot m -> key 8*(m>>2)+(m&3)

  const __bf16* Qp = Qb + (size_t)b * T_ * HS_;
  const __bf16* Kp = Kb + (size_t)b * T_ * HS_;
  const __bf16* Vp = Vt + (size_t)b * HS_ * T_;

  bf16x8 qf[2][4];
#pragma unroll
  for (int rt = 0; rt < 2; ++rt)
#pragma unroll
    for (int cs = 0; cs < 4; ++cs)
      qf[rt][cs] = *reinterpret_cast<const bf16x8*>(
          Qp + (size_t)(qb + rt * 16 + c) * HS_ + cs * 32 + g * 8);

  f32x4 acc[2][8];
#pragma unroll
  for (int i = 0; i < 2; ++i)
#pragma unroll
    for (int d = 0; d < 8; ++d) acc[i][d] = 0.f;
  float mrun[2] = {-INFINITY, -INFINITY};
  float lrun[2] = {0.f, 0.f};

  if (wid <= qt) {
    bf16x8 kreg[8];
    auto kload = [&](int kt) {
      const __bf16* kr = Kp + (size_t)(kt * 32 + kp) * HS_;
#pragma unroll
      for (int cs = 0; cs < 4; ++cs) {
        kreg[2 * cs]     = *reinterpret_cast<const bf16x8*>(kr + cs * 32 + g * 8);
        kreg[2 * cs + 1] = *reinterpret_cast<const bf16x8*>(kr + 4 * HS_ + cs * 32 + g * 8);
      }
    };
    kload(wid);

    for (int kt = wid; kt <= qt; kt += 4) {
      f32x4 s00 = 0.f, s01 = 0.f, s10 = 0.f, s11 = 0.f;
      __builtin_amdgcn_s_setprio(1);
#pragma unroll
      for (int cs = 0; cs < 4; ++cs) {
        s00 = MFMA(kreg[2 * cs], qf[0][cs], s00);
        s01 = MFMA(kreg[2 * cs + 1], qf[0][cs], s01);
        s10 = MFMA(kreg[2 * cs], qf[1][cs], s10);
        s11 = MFMA(kreg[2 * cs + 1], qf[1][cs], s11);
      }
      __builtin_amdgcn_s_setprio(0);

      if (kt + 4 <= qt) kload(kt + 4);        // prefetch next K tile

      bf16x8 vf[8];
      const __bf16* vr = Vp + kt * 32 + g * 8;
#pragma unroll
      for (int db = 0; db < 8; ++db)
        vf[db] = *reinterpret_cast<const bf16x8*>(vr + (size_t)(db * 16 + c) * T_);

      const bool maskt = (kt == qt);           // only the diagonal tile
      bf16x8 pb[2];
#pragma unroll
      for (int rt = 0; rt < 2; ++rt) {
        float p[8];
        const f32x4 sa = rt ? s10 : s00;
        const f32x4 sb = rt ? s11 : s01;
#pragma unroll
        for (int rr = 0; rr < 4; ++rr) { p[rr] = sa[rr]; p[4 + rr] = sb[rr]; }
        if (maskt) {
          const int lim = rt * 16 + c;
#pragma unroll
          for (int jj = 0; jj < 8; ++jj)
            if (8 * g + jj > lim) p[jj] = -INFINITY;
        }
        float t0 = fmaxf(fmaxf(p[0], p[1]), p[2]);
        float t1 = fmaxf(fmaxf(p[3], p[4]), p[5]);
        float t2 = fmaxf(fmaxf(p[6], p[7]), t0);
        float tmax = fmaxf(t1, t2);
        tmax = fmaxf(tmax, __shfl_xor(tmax, 16));
        tmax = fmaxf(tmax, __shfl_xor(tmax, 32));

        if (!__all(tmax <= mrun[rt] + 11.5415603f)) {   // defer-max, log2 units
          float mnew = fmaxf(mrun[rt], tmax);
          float al   = fexp2(mrun[rt] - mnew);
          mrun[rt] = mnew;
          lrun[rt] *= al;
#pragma unroll
          for (int db = 0; db < 8; ++db) acc[rt][db] *= al;
        }
        const float mc = mrun[rt];
#pragma unroll
        for (int jj = 0; jj < 8; ++jj) p[jj] = fexp2(p[jj] - mc);
        float ts = ((p[0] + p[1]) + (p[2] + p[3])) + ((p[4] + p[5]) + (p[6] + p[7]));
        ts += __shfl_xor(ts, 16);
        ts += __shfl_xor(ts, 32);
        lrun[rt] += ts;
#pragma unroll
        for (int jj = 0; jj < 8; ++jj) pb[rt][jj] = (__bf16)p[jj];
      }

      __builtin_amdgcn_s_setprio(1);
#pragma unroll
      for (int db = 0; db < 8; ++db) {
        acc[0][db] = MFMA(vf[db], pb[0], acc[0][db]);
        acc[1][db] = MFMA(vf[db], pb[1], acc[1][db]);
      }
      __builtin_amdgcn_s_setprio(0);
    }
  }

  // ---- combine the 4 waves' partial (m, l, O) ----
  if (g == 0) {
    sm[wid][c] = mrun[0]; sm[wid][16 + c] = mrun[1];
    sl[wid][c] = lrun[0]; sl[wid][16 + c] = lrun[1];
  }
  __syncthreads();

  float linv[2];
#pragma unroll
  for (int rt = 0; rt < 2; ++rt) {
    const int q = rt * 16 + c;
    float ms = fmaxf(fmaxf(sm[0][q], sm[1][q]), fmaxf(sm[2][q], sm[3][q]));
    float ls = fexp2(sm[0][q] - ms) * sl[0][q] + fexp2(sm[1][q] - ms) * sl[1][q]
             + fexp2(sm[2][q] - ms) * sl[2][q] + fexp2(sm[3][q] - ms) * sl[3][q];
    float al = fexp2(mrun[rt] - ms);
#pragma unroll
    for (int db = 0; db < 8; ++db) acc[rt][db] *= al;
    linv[rt] = 1.0f / ls;
  }

  auto store_buf = [&](float(*buf)[132]) {
#pragma unroll
    for (int rt = 0; rt < 2; ++rt)
#pragma unroll
      for (int db = 0; db < 8; ++db)
        *reinterpret_cast<f32x4*>(&buf[rt * 16 + c][db * 16 + 4 * g]) = acc[rt][db];
  };
  auto add_buf = [&](float(*buf)[132]) {
#pragma unroll
    for (int rt = 0; rt < 2; ++rt)
#pragma unroll
      for (int db = 0; db < 8; ++db)
        acc[rt][db] += *reinterpret_cast<const f32x4*>(&buf[rt * 16 + c][db * 16 + 4 * g]);
  };

  if (wid == 2) store_buf(bufA);
  if (wid == 3) store_buf(bufB);
  __syncthreads();
  if (wid == 0) add_buf(bufA);
  if (wid == 1) add_buf(bufB);
  __syncthreads();
  if (wid == 1) store_buf(bufA);
  __syncthreads();
  if (wid == 0) {
    add_buf(bufA);
    float* op = out + ((size_t)b * T_ + qb) * HS_;
#pragma unroll
    for (int rt = 0; rt < 2; ++rt)
#pragma unroll
      for (int db = 0; db < 8; ++db) {
        f32x4 v = acc[rt][db] * linv[rt];
        *reinterpret_cast<f32x4*>(op + (size_t)(rt * 16 + c) * HS_ + db * 16 + 4 * g) = v;
      }
  }
}

// ---------------------------------------------------------------------------
extern "C" void kernel_launch(void* const* d_in, const int* in_sizes, int n_in,
                              void* d_out, int out_size, void* d_ws, size_t ws_size,
                              hipStream_t stream) {
  const float* x  = (const float*)d_in[0];
  const float* Wk = (const float*)d_in[1];
  const float* Wq = (const float*)d_in[2];
  const float* Wv = (const float*)d_in[3];
  float* out = (float*)d_out;

  char* ws = (char*)d_ws;
  __bf16* Wt = (__bf16*)ws;                              // 768 KiB
  __bf16* Qb = (__bf16*)(ws + 786432);                   // 4 MiB
  __bf16* Kb = (__bf16*)(ws + 786432 + 4194304);         // 4 MiB
  __bf16* Vt = (__bf16*)(ws + 786432 + 8388608);         // 4 MiB (transposed V)

  prep_w_kernel<<<48, 256, 0, stream>>>(Wk, Wq, Wv, Wt);
  proj_kernel<<<512, 512, 0, stream>>>(x, Wt, Qb, Kb, Vt);
  attn_kernel<<<512, 256, 0, stream>>>(Qb, Kb, Vt, out);
}

// Round 5
// 172.769 us; speedup vs baseline: 1.0814x; 1.0037x over previous
//
#include <hip/hip_runtime.h>
#include <hip/hip_bf16.h>
#include <math.h>

#define B_  4
#define T_  4096
#define C_  1024
#define HS_ 128

using bf16x8 = __attribute__((ext_vector_type(8))) __bf16;
using bf16x4 = __attribute__((ext_vector_type(4))) __bf16;
using f32x4  = __attribute__((ext_vector_type(4))) float;

#define MFMA(a, b, c) __builtin_amdgcn_mfma_f32_16x16x32_bf16(a, b, c, 0, 0, 0)

// fast exp2 via v_exp_f32; trailing s_nop covers the 1-wait-state trans hazard
__device__ inline float fexp2(float x) {
  float r;
  asm volatile("v_exp_f32 %0, %1\n\ts_nop 0" : "=v"(r) : "v"(x));
  return r;
}

// ---------------------------------------------------------------------------
// Kernel 1: W fp32 [1024][128] -> Wt bf16 [3][128][1024] via LDS transpose.
// m=0: Wq scaled by 1/sqrt(128) * log2(e)  (exp2-domain softmax).
// ---------------------------------------------------------------------------
__global__ __launch_bounds__(256) void prep_w_kernel(
    const float* __restrict__ Wk, const float* __restrict__ Wq,
    const float* __restrict__ Wv, __bf16* __restrict__ Wt) {
  const int m  = blockIdx.x >> 4;        // 0..2
  const int k0 = (blockIdx.x & 15) * 64; // k-slab base
  const float* W = (m == 0) ? Wq : ((m == 1) ? Wk : Wv);
  const float scale = (m == 0) ? (0.08838834764831845f * 1.4426950408889634f) : 1.0f;
  __shared__ __bf16 tile[128][72];       // [n][k-within-slab], padded
  const int t = threadIdx.x;
#pragma unroll
  for (int p = 0; p < 8; ++p) {
    int e  = p * 1024 + t * 4;
    int r  = e >> 7;                     // 0..63
    int cc = e & 127;
    float4 w = *reinterpret_cast<const float4*>(&W[(size_t)(k0 + r) * HS_ + cc]);
    tile[cc + 0][r] = (__bf16)(w.x * scale);
    tile[cc + 1][r] = (__bf16)(w.y * scale);
    tile[cc + 2][r] = (__bf16)(w.z * scale);
    tile[cc + 3][r] = (__bf16)(w.w * scale);
  }
  __syncthreads();
#pragma unroll
  for (int p = 0; p < 4; ++p) {
    int e  = p * 2048 + t * 8;
    int n  = e >> 6;                     // 0..127
    int kk = e & 63;
    bf16x8 v;
#pragma unroll
    for (int jj = 0; jj < 8; ++jj) v[jj] = tile[n][kk + jj];
    *reinterpret_cast<bf16x8*>(&Wt[((size_t)m * 128 + n) * C_ + k0 + kk]) = v;
  }
}

__device__ inline bf16x8 cvt8p(float4 u, float4 v) {
  bf16x8 r;
  r[0] = (__bf16)u.x; r[1] = (__bf16)u.y; r[2] = (__bf16)u.z; r[3] = (__bf16)u.w;
  r[4] = (__bf16)v.x; r[5] = (__bf16)v.y; r[6] = (__bf16)v.z; r[7] = (__bf16)v.w;
  return r;
}

// ---------------------------------------------------------------------------
// Kernel 2: projections. 512 blocks x 32 rows, 8 waves; wave owns 3 (m,nt)
// units (acc[3][2] -> only 24 accum regs; ~95 live arch VGPRs, NO launch-
// bounds cap: the (N,4) cap forced 64 arch VGPRs + spills in rounds 2-3).
// 2-stage software pipeline of x (fp32->bf16 in-reg) and W fragments.
// Q,K row-major bf16 [B*T][128]; V transposed [B][128][T].
// ---------------------------------------------------------------------------
__global__ __launch_bounds__(512) void proj_kernel(
    const float* __restrict__ x, const __bf16* __restrict__ Wt,
    __bf16* __restrict__ Qb, __bf16* __restrict__ Kb, __bf16* __restrict__ Vt) {
  const int tid = threadIdx.x;
  const int wid = tid >> 6;      // 0..7
  const int l   = tid & 63;
  const int c   = l & 15;        // A-row / B-col slot
  const int g   = l >> 4;        // k-group
  const int rbase = blockIdx.x * 32;

  f32x4 acc[3][2];
#pragma unroll
  for (int i = 0; i < 3; ++i) { acc[i][0] = 0.f; acc[i][1] = 0.f; }

  const float* xr0 = x + (size_t)(rbase + c) * C_ + g * 8;
  const float* xr1 = xr0 + 16 * C_;
  const __bf16* wb[3];
#pragma unroll
  for (int i = 0; i < 3; ++i) {
    int u = wid * 3 + i;
    wb[i] = Wt + ((size_t)(u >> 3) * 128 + (u & 7) * 16 + c) * C_ + g * 8;
  }

  float4 xu0 = *reinterpret_cast<const float4*>(xr0);
  float4 xv0 = *reinterpret_cast<const float4*>(xr0 + 4);
  float4 yu0 = *reinterpret_cast<const float4*>(xr1);
  float4 yv0 = *reinterpret_cast<const float4*>(xr1 + 4);
  bf16x8 b0[3];
#pragma unroll
  for (int i = 0; i < 3; ++i) b0[i] = *reinterpret_cast<const bf16x8*>(wb[i]);

  for (int cb = 0; cb < C_; cb += 64) {
    // prefetch stage B (cb+32) — always in-bounds (cb <= 960)
    float4 xu1, xv1, yu1, yv1; bf16x8 b1[3];
    {
      const float* p0 = xr0 + cb + 32;
      const float* p1 = xr1 + cb + 32;
      xu1 = *reinterpret_cast<const float4*>(p0);
      xv1 = *reinterpret_cast<const float4*>(p0 + 4);
      yu1 = *reinterpret_cast<const float4*>(p1);
      yv1 = *reinterpret_cast<const float4*>(p1 + 4);
#pragma unroll
      for (int i = 0; i < 3; ++i) b1[i] = *reinterpret_cast<const bf16x8*>(wb[i] + cb + 32);
    }
    // compute stage A
    {
      bf16x8 a0 = cvt8p(xu0, xv0);
      bf16x8 a1 = cvt8p(yu0, yv0);
#pragma unroll
      for (int i = 0; i < 3; ++i) {
        acc[i][0] = MFMA(a0, b0[i], acc[i][0]);
        acc[i][1] = MFMA(a1, b0[i], acc[i][1]);
      }
    }
    // prefetch stage A of next iter (cb+64)
    if (cb + 64 < C_) {
      const float* p0 = xr0 + cb + 64;
      const float* p1 = xr1 + cb + 64;
      xu0 = *reinterpret_cast<const float4*>(p0);
      xv0 = *reinterpret_cast<const float4*>(p0 + 4);
      yu0 = *reinterpret_cast<const float4*>(p1);
      yv0 = *reinterpret_cast<const float4*>(p1 + 4);
#pragma unroll
      for (int i = 0; i < 3; ++i) b0[i] = *reinterpret_cast<const bf16x8*>(wb[i] + cb + 64);
    }
    // compute stage B
    {
      bf16x8 a0 = cvt8p(xu1, xv1);
      bf16x8 a1 = cvt8p(yu1, yv1);
#pragma unroll
      for (int i = 0; i < 3; ++i) {
        acc[i][0] = MFMA(a0, b1[i], acc[i][0]);
        acc[i][1] = MFMA(a1, b1[i], acc[i][1]);
      }
    }
  }

#pragma unroll
  for (int i = 0; i < 3; ++i) {
    const int u = wid * 3 + i;
    const int m = u >> 3, nt = u & 7;
    if (m < 2) {
      __bf16* dst = (m == 0) ? Qb : Kb;
#pragma unroll
      for (int rt = 0; rt < 2; ++rt)
#pragma unroll
        for (int rr = 0; rr < 4; ++rr)
          dst[(size_t)(rbase + rt * 16 + 4 * g + rr) * HS_ + nt * 16 + c] =
              (__bf16)acc[i][rt][rr];
    } else {
#pragma unroll
      for (int rt = 0; rt < 2; ++rt) {
        int row = rbase + rt * 16 + 4 * g;
        int bb  = row >> 12;
        int t   = row & 4095;
        bf16x4 v4;
#pragma unroll
        for (int rr = 0; rr < 4; ++rr) v4[rr] = (__bf16)acc[i][rt][rr];
        *reinterpret_cast<bf16x4*>(Vt + ((size_t)bb * HS_ + nt * 16 + c) * T_ + t) = v4;
      }
    }
  }
}

// ---------------------------------------------------------------------------
// Kernel 3: causal flash attention. 4 waves/block; each wave owns the FULL
// 32 q-rows (acc[2][8]) and a 4-way kt split (kt = wid, wid+4, ...).
// S^T = mfma(K_perm, Q^T): softmax stats lane-column-local; P per-lane IS
// the PV B-fragment. K next-tile register prefetch; V loads fly under
// softmax VALU. exp2-domain (log2e folded into Wq). 4-wave LDS combine.
// b = (bid&7)>>1 gives batch->XCD affinity (K/V working set < 4MB L2/XCD).
// ---------------------------------------------------------------------------
__global__ __launch_bounds__(256, 2) void attn_kernel(
    const __bf16* __restrict__ Qb, const __bf16* __restrict__ Kb,
    const __bf16* __restrict__ Vt, float* __restrict__ out) {
  __shared__ float sm[4][32];
  __shared__ float sl[4][32];
  __shared__ float bufA[32][132];
  __shared__ float bufB[32][132];

  const int tid = threadIdx.x;
  const int wid = tid >> 6;
  const int l   = tid & 63;
  const int c   = l & 15;
  const int g   = l >> 4;
  const int bid = blockIdx.x;
  const int b   = (bid & 7) >> 1;                    // XCD-affine batch
  const int j   = ((bid >> 3) << 1) | (bid & 1);     // 0..127
  const int qt  = (j < 64) ? (127 - j) : (j - 64);   // big tiles dispatched first
  const int qb  = qt * 32;
  const int kp  = ((l & 12) << 1) | (l & 3);         // A-slot m -> key 8*(m>>2)+(m&3)

  const __bf16* Qp = Qb + (size_t)b * T_ * HS_;
  const __bf16* Kp = Kb + (size_t)b * T_ * HS_;
  const __bf16* Vp = Vt + (size_t)b * HS_ * T_;

  bf16x8 qf[2][4];
#pragma unroll
  for (int rt = 0; rt < 2; ++rt)
#pragma unroll
    for (int cs = 0; cs < 4; ++cs)
      qf[rt][cs] = *reinterpret_cast<const bf16x8*>(
          Qp + (size_t)(qb + rt * 16 + c) * HS_ + cs * 32 + g * 8);

  f32x4 acc[2][8];
#pragma unroll
  for (int i = 0; i < 2; ++i)
#pragma unroll
    for (int d = 0; d < 8; ++d) acc[i][d] = 0.f;
  float mrun[2] = {-INFINITY, -INFINITY};
  float lrun[2] = {0.f, 0.f};

  if (wid <= qt) {
    bf16x8 kreg[8];
    auto kload = [&](int kt) {
      const __bf16* kr = Kp + (size_t)(kt * 32 + kp) * HS_;
#pragma unroll
      for (int cs = 0; cs < 4; ++cs) {
        kreg[2 * cs]     = *reinterpret_cast<const bf16x8*>(kr + cs * 32 + g * 8);
        kreg[2 * cs + 1] = *reinterpret_cast<const bf16x8*>(kr + 4 * HS_ + cs * 32 + g * 8);
      }
    };
    kload(wid);

    for (int kt = wid; kt <= qt; kt += 4) {
      f32x4 s00 = 0.f, s01 = 0.f, s10 = 0.f, s11 = 0.f;
      __builtin_amdgcn_s_setprio(1);
#pragma unroll
      for (int cs = 0; cs < 4; ++cs) {
        s00 = MFMA(kreg[2 * cs], qf[0][cs], s00);
        s01 = MFMA(kreg[2 * cs + 1], qf[0][cs], s01);
        s10 = MFMA(kreg[2 * cs], qf[1][cs], s10);
        s11 = MFMA(kreg[2 * cs + 1], qf[1][cs], s11);
      }
      __builtin_amdgcn_s_setprio(0);

      if (kt + 4 <= qt) kload(kt + 4);        // prefetch next K tile

      bf16x8 vf[8];
      const __bf16* vr = Vp + kt * 32 + g * 8;
#pragma unroll
      for (int db = 0; db < 8; ++db)
        vf[db] = *reinterpret_cast<const bf16x8*>(vr + (size_t)(db * 16 + c) * T_);

      const bool maskt = (kt == qt);           // only the diagonal tile
      bf16x8 pb[2];
#pragma unroll
      for (int rt = 0; rt < 2; ++rt) {
        float p[8];
        const f32x4 sa = rt ? s10 : s00;
        const f32x4 sb = rt ? s11 : s01;
#pragma unroll
        for (int rr = 0; rr < 4; ++rr) { p[rr] = sa[rr]; p[4 + rr] = sb[rr]; }
        if (maskt) {
          const int lim = rt * 16 + c;
#pragma unroll
          for (int jj = 0; jj < 8; ++jj)
            if (8 * g + jj > lim) p[jj] = -INFINITY;
        }
        float t0 = fmaxf(fmaxf(p[0], p[1]), p[2]);
        float t1 = fmaxf(fmaxf(p[3], p[4]), p[5]);
        float t2 = fmaxf(fmaxf(p[6], p[7]), t0);
        float tmax = fmaxf(t1, t2);
        tmax = fmaxf(tmax, __shfl_xor(tmax, 16));
        tmax = fmaxf(tmax, __shfl_xor(tmax, 32));

        if (!__all(tmax <= mrun[rt] + 11.5415603f)) {   // defer-max, log2 units
          float mnew = fmaxf(mrun[rt], tmax);
          float al   = fexp2(mrun[rt] - mnew);
          mrun[rt] = mnew;
          lrun[rt] *= al;
#pragma unroll
          for (int db = 0; db < 8; ++db) acc[rt][db] *= al;
        }
        const float mc = mrun[rt];
#pragma unroll
        for (int jj = 0; jj < 8; ++jj) p[jj] = fexp2(p[jj] - mc);
        float ts = ((p[0] + p[1]) + (p[2] + p[3])) + ((p[4] + p[5]) + (p[6] + p[7]));
        ts += __shfl_xor(ts, 16);
        ts += __shfl_xor(ts, 32);
        lrun[rt] += ts;
#pragma unroll
        for (int jj = 0; jj < 8; ++jj) pb[rt][jj] = (__bf16)p[jj];
      }

      __builtin_amdgcn_s_setprio(1);
#pragma unroll
      for (int db = 0; db < 8; ++db) {
        acc[0][db] = MFMA(vf[db], pb[0], acc[0][db]);
        acc[1][db] = MFMA(vf[db], pb[1], acc[1][db]);
      }
      __builtin_amdgcn_s_setprio(0);
    }
  }

  // ---- combine the 4 waves' partial (m, l, O) ----
  if (g == 0) {
    sm[wid][c] = mrun[0]; sm[wid][16 + c] = mrun[1];
    sl[wid][c] = lrun[0]; sl[wid][16 + c] = lrun[1];
  }
  __syncthreads();

  float linv[2];
#pragma unroll
  for (int rt = 0; rt < 2; ++rt) {
    const int q = rt * 16 + c;
    float ms = fmaxf(fmaxf(sm[0][q], sm[1][q]), fmaxf(sm[2][q], sm[3][q]));
    float ls = fexp2(sm[0][q] - ms) * sl[0][q] + fexp2(sm[1][q] - ms) * sl[1][q]
             + fexp2(sm[2][q] - ms) * sl[2][q] + fexp2(sm[3][q] - ms) * sl[3][q];
    float al = fexp2(mrun[rt] - ms);
#pragma unroll
    for (int db = 0; db < 8; ++db) acc[rt][db] *= al;
    linv[rt] = 1.0f / ls;
  }

  auto store_buf = [&](float(*buf)[132]) {
#pragma unroll
    for (int rt = 0; rt < 2; ++rt)
#pragma unroll
      for (int db = 0; db < 8; ++db)
        *reinterpret_cast<f32x4*>(&buf[rt * 16 + c][db * 16 + 4 * g]) = acc[rt][db];
  };
  auto add_buf = [&](float(*buf)[132]) {
#pragma unroll
    for (int rt = 0; rt < 2; ++rt)
#pragma unroll
      for (int db = 0; db < 8; ++db)
        acc[rt][db] += *reinterpret_cast<const f32x4*>(&buf[rt * 16 + c][db * 16 + 4 * g]);
  };

  if (wid == 2) store_buf(bufA);
  if (wid == 3) store_buf(bufB);
  __syncthreads();
  if (wid == 0) add_buf(bufA);
  if (wid == 1) add_buf(bufB);
  __syncthreads();
  if (wid == 1) store_buf(bufA);
  __syncthreads();
  if (wid == 0) {
    add_buf(bufA);
    float* op = out + ((size_t)b * T_ + qb) * HS_;
#pragma unroll
    for (int rt = 0; rt < 2; ++rt)
#pragma unroll
      for (int db = 0; db < 8; ++db) {
        f32x4 v = acc[rt][db] * linv[rt];
        *reinterpret_cast<f32x4*>(op + (size_t)(rt * 16 + c) * HS_ + db * 16 + 4 * g) = v;
      }
  }
}

// ---------------------------------------------------------------------------
extern "C" void kernel_launch(void* const* d_in, const int* in_sizes, int n_in,
                              void* d_out, int out_size, void* d_ws, size_t ws_size,
                              hipStream_t stream) {
  const float* x  = (const float*)d_in[0];
  const float* Wk = (const float*)d_in[1];
  const float* Wq = (const float*)d_in[2];
  const float* Wv = (const float*)d_in[3];
  float* out = (float*)d_out;

  char* ws = (char*)d_ws;
  __bf16* Wt = (__bf16*)ws;                              // 768 KiB
  __bf16* Qb = (__bf16*)(ws + 786432);                   // 4 MiB
  __bf16* Kb = (__bf16*)(ws + 786432 + 4194304);         // 4 MiB
  __bf16* Vt = (__bf16*)(ws + 786432 + 8388608);         // 4 MiB (transposed V)

  prep_w_kernel<<<48, 256, 0, stream>>>(Wk, Wq, Wv, Wt);
  proj_kernel<<<512, 512, 0, stream>>>(x, Wt, Qb, Kb, Vt);
  attn_kernel<<<512, 256, 0, stream>>>(Qb, Kb, Vt, out);
}

// Round 6
// 123.272 us; speedup vs baseline: 1.5156x; 1.4015x over previous
//
#include <hip/hip_runtime.h>
#include <hip/hip_bf16.h>
#include <math.h>

#define B_  4
#define T_  4096
#define C_  1024
#define HS_ 128

using bf16x8 = __attribute__((ext_vector_type(8))) __bf16;
using bf16x4 = __attribute__((ext_vector_type(4))) __bf16;
using f32x4  = __attribute__((ext_vector_type(4))) float;

#define MFMA(a, b, c) __builtin_amdgcn_mfma_f32_16x16x32_bf16(a, b, c, 0, 0, 0)

typedef __attribute__((address_space(1))) const float gfloat;
typedef __attribute__((address_space(3))) float lfloat;

// fast exp2 via v_exp_f32; trailing s_nop covers the 1-wait-state trans hazard
__device__ inline float fexp2(float x) {
  float r;
  asm volatile("v_exp_f32 %0, %1\n\ts_nop 0" : "=v"(r) : "v"(x));
  return r;
}

// ---------------------------------------------------------------------------
// Kernel 1: W fp32 [1024][128] -> Wt bf16 [3][128][1024] via LDS transpose.
// m=0: Wq scaled by 1/sqrt(128) * log2(e)  (exp2-domain softmax).
// ---------------------------------------------------------------------------
__global__ __launch_bounds__(256) void prep_w_kernel(
    const float* __restrict__ Wk, const float* __restrict__ Wq,
    const float* __restrict__ Wv, __bf16* __restrict__ Wt) {
  const int m  = blockIdx.x >> 4;        // 0..2
  const int k0 = (blockIdx.x & 15) * 64; // k-slab base
  const float* W = (m == 0) ? Wq : ((m == 1) ? Wk : Wv);
  const float scale = (m == 0) ? (0.08838834764831845f * 1.4426950408889634f) : 1.0f;
  __shared__ __bf16 tile[128][72];       // [n][k-within-slab], padded
  const int t = threadIdx.x;
#pragma unroll
  for (int p = 0; p < 8; ++p) {
    int e  = p * 1024 + t * 4;
    int r  = e >> 7;                     // 0..63
    int cc = e & 127;
    float4 w = *reinterpret_cast<const float4*>(&W[(size_t)(k0 + r) * HS_ + cc]);
    tile[cc + 0][r] = (__bf16)(w.x * scale);
    tile[cc + 1][r] = (__bf16)(w.y * scale);
    tile[cc + 2][r] = (__bf16)(w.z * scale);
    tile[cc + 3][r] = (__bf16)(w.w * scale);
  }
  __syncthreads();
#pragma unroll
  for (int p = 0; p < 4; ++p) {
    int e  = p * 2048 + t * 8;
    int n  = e >> 6;                     // 0..127
    int kk = e & 63;
    bf16x8 v;
#pragma unroll
    for (int jj = 0; jj < 8; ++jj) v[jj] = tile[n][kk + jj];
    *reinterpret_cast<bf16x8*>(&Wt[((size_t)m * 128 + n) * C_ + k0 + kk]) = v;
  }
}

__device__ inline bf16x8 cvt8p(float4 u, float4 v) {
  bf16x8 r;
  r[0] = (__bf16)u.x; r[1] = (__bf16)u.y; r[2] = (__bf16)u.z; r[3] = (__bf16)u.w;
  r[4] = (__bf16)v.x; r[5] = (__bf16)v.y; r[6] = (__bf16)v.z; r[7] = (__bf16)v.w;
  return r;
}

// ---------------------------------------------------------------------------
// Kernel 2: projections, LDS-staged (R5 post-mortem: register-staged prefetch
// was serialized by the allocator's 56-VGPR occupancy choice; global_load_lds
// keeps in-flight data out of VGPRs entirely).
// Block = 32 rows, 8 waves, K-step 128: x-tile [32][128] fp32 = 16KB, 2 bufs.
// Stage: 2 global_load_lds dwordx4 per wave, LINEAR dest; bank-conflict-free
// via BOTH-sides XOR swizzle (chunk ^= row&15) applied to the per-lane GLOBAL
// source and the ds_read address (same involution; rule #21 / T2).
// Wave owns 3 (m,nt) units; W frags read from L2 (768 KB resident).
// Q,K row-major bf16 [B*T][128]; V transposed [B][128][T].
// ---------------------------------------------------------------------------
__global__ __launch_bounds__(512) void proj_kernel(
    const float* __restrict__ x, const __bf16* __restrict__ Wt,
    __bf16* __restrict__ Qb, __bf16* __restrict__ Kb, __bf16* __restrict__ Vt) {
  __shared__ float xs[2][32 * 128];      // 32 KB
  const int tid = threadIdx.x;
  const int wid = tid >> 6;      // 0..7
  const int l   = tid & 63;
  const int c   = l & 15;        // A-row / B-col slot
  const int g   = l >> 4;        // k-group
  const int rbase = blockIdx.x * 32;

  f32x4 acc[3][2];
#pragma unroll
  for (int i = 0; i < 3; ++i) { acc[i][0] = 0.f; acc[i][1] = 0.f; }

  const __bf16* wb[3];
#pragma unroll
  for (int i = 0; i < 3; ++i) {
    int u = wid * 3 + i;
    wb[i] = Wt + ((size_t)(u >> 3) * 128 + (u & 7) * 16 + c) * C_ + g * 8;
  }

  // staging geometry: tile has 32 rows x 32 chunks (16B). Wave w, instr k2,
  // lane l -> dest chunk w*128 + k2*64 + l; row = chunk>>5; p = l&31;
  // source chunk-in-row = p ^ (row&15).
  const int row0 = wid * 4 + (l >> 5);
  const int row1 = row0 + 2;
  const int p_in = l & 31;
  const int src0 = p_in ^ (row0 & 15);
  const int src1 = p_in ^ (row1 & 15);
  const float* gsrc0 = x + (size_t)(rbase + row0) * C_ + src0 * 4;
  const float* gsrc1 = x + (size_t)(rbase + row1) * C_ + src1 * 4;

  auto stage = [&](int t, int buf) {
    __builtin_amdgcn_global_load_lds((gfloat*)(gsrc0 + t * 128),
        (lfloat*)&xs[buf][wid * 512], 16, 0, 0);
    __builtin_amdgcn_global_load_lds((gfloat*)(gsrc1 + t * 128),
        (lfloat*)&xs[buf][wid * 512 + 256], 16, 0, 0);
  };

  stage(0, 0);
  asm volatile("s_waitcnt vmcnt(0)" ::: "memory");
  __syncthreads();

  for (int t = 0; t < 8; ++t) {
    const int cur = t & 1;
    if (t + 1 < 8) stage(t + 1, cur ^ 1);
    const float* xt = &xs[cur][0];
    const int cb = t * 128;
#pragma unroll
    for (int ksub = 0; ksub < 4; ++ksub) {
      bf16x8 bfr[3];
#pragma unroll
      for (int i = 0; i < 3; ++i)
        bfr[i] = *reinterpret_cast<const bf16x8*>(wb[i] + cb + ksub * 32);
#pragma unroll
      for (int rt = 0; rt < 2; ++rt) {
        const int rr = rt * 16 + c;          // rr & 15 == c
        const int q  = ksub * 8 + g * 2;     // 16B-chunk index pair (q, q+1)
        float4 lo = *reinterpret_cast<const float4*>(&xt[rr * 128 + ((q ^ c) << 2)]);
        float4 hi = *reinterpret_cast<const float4*>(&xt[rr * 128 + (((q + 1) ^ c) << 2)]);
        bf16x8 a = cvt8p(lo, hi);
#pragma unroll
        for (int i = 0; i < 3; ++i) acc[i][rt] = MFMA(a, bfr[i], acc[i][rt]);
      }
    }
    asm volatile("s_waitcnt vmcnt(0)" ::: "memory");
    __syncthreads();
  }

#pragma unroll
  for (int i = 0; i < 3; ++i) {
    const int u = wid * 3 + i;
    const int m = u >> 3, nt = u & 7;
    if (m < 2) {
      __bf16* dst = (m == 0) ? Qb : Kb;
#pragma unroll
      for (int rt = 0; rt < 2; ++rt)
#pragma unroll
        for (int rr = 0; rr < 4; ++rr)
          dst[(size_t)(rbase + rt * 16 + 4 * g + rr) * HS_ + nt * 16 + c] =
              (__bf16)acc[i][rt][rr];
    } else {
#pragma unroll
      for (int rt = 0; rt < 2; ++rt) {
        int row = rbase + rt * 16 + 4 * g;
        int bb  = row >> 12;
        int t2  = row & 4095;
        bf16x4 v4;
#pragma unroll
        for (int rr = 0; rr < 4; ++rr) v4[rr] = (__bf16)acc[i][rt][rr];
        *reinterpret_cast<bf16x4*>(Vt + ((size_t)bb * HS_ + nt * 16 + c) * T_ + t2) = v4;
      }
    }
  }
}

// ---------------------------------------------------------------------------
// Kernel 3: causal flash attention. 4 waves/block; each wave owns the FULL
// 32 q-rows (acc[2][8]) and a 4-way kt split (kt = wid, wid+4, ...).
// S^T = mfma(K_perm, Q^T): softmax stats lane-column-local; P per-lane IS
// the PV B-fragment. K next-tile register prefetch; V loads fly under
// softmax VALU. exp2-domain (log2e folded into Wq). 4-wave LDS combine.
// b = (bid&7)>>1 gives batch->XCD affinity (K/V working set < 4MB L2/XCD).
// ---------------------------------------------------------------------------
__global__ __launch_bounds__(256, 2) void attn_kernel(
    const __bf16* __restrict__ Qb, const __bf16* __restrict__ Kb,
    const __bf16* __restrict__ Vt, float* __restrict__ out) {
  __shared__ float sm[4][32];
  __shared__ float sl[4][32];
  __shared__ float bufA[32][132];
  __shared__ float bufB[32][132];

  const int tid = threadIdx.x;
  const int wid = tid >> 6;
  const int l   = tid & 63;
  const int c   = l & 15;
  const int g   = l >> 4;
  const int bid = blockIdx.x;
  const int b   = (bid & 7) >> 1;                    // XCD-affine batch
  const int j   = ((bid >> 3) << 1) | (bid & 1);     // 0..127
  const int qt  = (j < 64) ? (127 - j) : (j - 64);   // big tiles dispatched first
  const int qb  = qt * 32;
  const int kp  = ((l & 12) << 1) | (l & 3);         // A-slot m -> key 8*(m>>2)+(m&3)

  const __bf16* Qp = Qb + (size_t)b * T_ * HS_;
  const __bf16* Kp = Kb + (size_t)b * T_ * HS_;
  const __bf16* Vp = Vt + (size_t)b * HS_ * T_;

  bf16x8 qf[2][4];
#pragma unroll
  for (int rt = 0; rt < 2; ++rt)
#pragma unroll
    for (int cs = 0; cs < 4; ++cs)
      qf[rt][cs] = *reinterpret_cast<const bf16x8*>(
          Qp + (size_t)(qb + rt * 16 + c) * HS_ + cs * 32 + g * 8);

  f32x4 acc[2][8];
#pragma unroll
  for (int i = 0; i < 2; ++i)
#pragma unroll
    for (int d = 0; d < 8; ++d) acc[i][d] = 0.f;
  float mrun[2] = {-INFINITY, -INFINITY};
  float lrun[2] = {0.f, 0.f};

  if (wid <= qt) {
    bf16x8 kreg[8];
    auto kload = [&](int kt) {
      const __bf16* kr = Kp + (size_t)(kt * 32 + kp) * HS_;
#pragma unroll
      for (int cs = 0; cs < 4; ++cs) {
        kreg[2 * cs]     = *reinterpret_cast<const bf16x8*>(kr + cs * 32 + g * 8);
        kreg[2 * cs + 1] = *reinterpret_cast<const bf16x8*>(kr + 4 * HS_ + cs * 32 + g * 8);
      }
    };
    kload(wid);

    for (int kt = wid; kt <= qt; kt += 4) {
      f32x4 s00 = 0.f, s01 = 0.f, s10 = 0.f, s11 = 0.f;
      __builtin_amdgcn_s_setprio(1);
#pragma unroll
      for (int cs = 0; cs < 4; ++cs) {
        s00 = MFMA(kreg[2 * cs], qf[0][cs], s00);
        s01 = MFMA(kreg[2 * cs + 1], qf[0][cs], s01);
        s10 = MFMA(kreg[2 * cs], qf[1][cs], s10);
        s11 = MFMA(kreg[2 * cs + 1], qf[1][cs], s11);
      }
      __builtin_amdgcn_s_setprio(0);

      if (kt + 4 <= qt) kload(kt + 4);        // prefetch next K tile

      bf16x8 vf[8];
      const __bf16* vr = Vp + kt * 32 + g * 8;
#pragma unroll
      for (int db = 0; db < 8; ++db)
        vf[db] = *reinterpret_cast<const bf16x8*>(vr + (size_t)(db * 16 + c) * T_);

      const bool maskt = (kt == qt);           // only the diagonal tile
      bf16x8 pb[2];
#pragma unroll
      for (int rt = 0; rt < 2; ++rt) {
        float p[8];
        const f32x4 sa = rt ? s10 : s00;
        const f32x4 sb = rt ? s11 : s01;
#pragma unroll
        for (int rr = 0; rr < 4; ++rr) { p[rr] = sa[rr]; p[4 + rr] = sb[rr]; }
        if (maskt) {
          const int lim = rt * 16 + c;
#pragma unroll
          for (int jj = 0; jj < 8; ++jj)
            if (8 * g + jj > lim) p[jj] = -INFINITY;
        }
        float t0 = fmaxf(fmaxf(p[0], p[1]), p[2]);
        float t1 = fmaxf(fmaxf(p[3], p[4]), p[5]);
        float t2 = fmaxf(fmaxf(p[6], p[7]), t0);
        float tmax = fmaxf(t1, t2);
        tmax = fmaxf(tmax, __shfl_xor(tmax, 16));
        tmax = fmaxf(tmax, __shfl_xor(tmax, 32));

        if (!__all(tmax <= mrun[rt] + 11.5415603f)) {   // defer-max, log2 units
          float mnew = fmaxf(mrun[rt], tmax);
          float al   = fexp2(mrun[rt] - mnew);
          mrun[rt] = mnew;
          lrun[rt] *= al;
#pragma unroll
          for (int db = 0; db < 8; ++db) acc[rt][db] *= al;
        }
        const float mc = mrun[rt];
#pragma unroll
        for (int jj = 0; jj < 8; ++jj) p[jj] = fexp2(p[jj] - mc);
        float ts = ((p[0] + p[1]) + (p[2] + p[3])) + ((p[4] + p[5]) + (p[6] + p[7]));
        ts += __shfl_xor(ts, 16);
        ts += __shfl_xor(ts, 32);
        lrun[rt] += ts;
#pragma unroll
        for (int jj = 0; jj < 8; ++jj) pb[rt][jj] = (__bf16)p[jj];
      }

      __builtin_amdgcn_s_setprio(1);
#pragma unroll
      for (int db = 0; db < 8; ++db) {
        acc[0][db] = MFMA(vf[db], pb[0], acc[0][db]);
        acc[1][db] = MFMA(vf[db], pb[1], acc[1][db]);
      }
      __builtin_amdgcn_s_setprio(0);
    }
  }

  // ---- combine the 4 waves' partial (m, l, O) ----
  if (g == 0) {
    sm[wid][c] = mrun[0]; sm[wid][16 + c] = mrun[1];
    sl[wid][c] = lrun[0]; sl[wid][16 + c] = lrun[1];
  }
  __syncthreads();

  float linv[2];
#pragma unroll
  for (int rt = 0; rt < 2; ++rt) {
    const int q = rt * 16 + c;
    float ms = fmaxf(fmaxf(sm[0][q], sm[1][q]), fmaxf(sm[2][q], sm[3][q]));
    float ls = fexp2(sm[0][q] - ms) * sl[0][q] + fexp2(sm[1][q] - ms) * sl[1][q]
             + fexp2(sm[2][q] - ms) * sl[2][q] + fexp2(sm[3][q] - ms) * sl[3][q];
    float al = fexp2(mrun[rt] - ms);
#pragma unroll
    for (int db = 0; db < 8; ++db) acc[rt][db] *= al;
    linv[rt] = 1.0f / ls;
  }

  auto store_buf = [&](float(*buf)[132]) {
#pragma unroll
    for (int rt = 0; rt < 2; ++rt)
#pragma unroll
      for (int db = 0; db < 8; ++db)
        *reinterpret_cast<f32x4*>(&buf[rt * 16 + c][db * 16 + 4 * g]) = acc[rt][db];
  };
  auto add_buf = [&](float(*buf)[132]) {
#pragma unroll
    for (int rt = 0; rt < 2; ++rt)
#pragma unroll
      for (int db = 0; db < 8; ++db)
        acc[rt][db] += *reinterpret_cast<const f32x4*>(&buf[rt * 16 + c][db * 16 + 4 * g]);
  };

  if (wid == 2) store_buf(bufA);
  if (wid == 3) store_buf(bufB);
  __syncthreads();
  if (wid == 0) add_buf(bufA);
  if (wid == 1) add_buf(bufB);
  __syncthreads();
  if (wid == 1) store_buf(bufA);
  __syncthreads();
  if (wid == 0) {
    add_buf(bufA);
    float* op = out + ((size_t)b * T_ + qb) * HS_;
#pragma unroll
    for (int rt = 0; rt < 2; ++rt)
#pragma unroll
      for (int db = 0; db < 8; ++db) {
        f32x4 v = acc[rt][db] * linv[rt];
        *reinterpret_cast<f32x4*>(op + (size_t)(rt * 16 + c) * HS_ + db * 16 + 4 * g) = v;
      }
  }
}

// ---------------------------------------------------------------------------
extern "C" void kernel_launch(void* const* d_in, const int* in_sizes, int n_in,
                              void* d_out, int out_size, void* d_ws, size_t ws_size,
                              hipStream_t stream) {
  const float* x  = (const float*)d_in[0];
  const float* Wk = (const float*)d_in[1];
  const float* Wq = (const float*)d_in[2];
  const float* Wv = (const float*)d_in[3];
  float* out = (float*)d_out;

  char* ws = (char*)d_ws;
  __bf16* Wt = (__bf16*)ws;                              // 768 KiB
  __bf16* Qb = (__bf16*)(ws + 786432);                   // 4 MiB
  __bf16* Kb = (__bf16*)(ws + 786432 + 4194304);         // 4 MiB
  __bf16* Vt = (__bf16*)(ws + 786432 + 8388608);         // 4 MiB (transposed V)

  prep_w_kernel<<<48, 256, 0, stream>>>(Wk, Wq, Wv, Wt);
  proj_kernel<<<512, 512, 0, stream>>>(x, Wt, Qb, Kb, Vt);
  attn_kernel<<<512, 256, 0, stream>>>(Qb, Kb, Vt, out);
}